// Round 3
// baseline (173.639 us; speedup 1.0000x reference)
//
#include <hip/hip_runtime.h>
#include <math.h>

// Problem constants (N,C,H,W,D) = (64, 3, 256, 256, 512)
#define N_B 64
#define C_CH 3
#define H_IMG 256
#define W_IMG 256
#define D_FEAT 512

#define OUT_OFF_GRID   12582912
#define OUT_OFF_MATRIX 20971520
#define OUT_OFF_AFFINE 20971904

// pyramid (NHWC layout, c innermost) sizes in floats
#define PYR1_SZ (N_B * 128 * 128 * 3)
#define PYR2_SZ (N_B * 64 * 64 * 3)
#define PYR3_SZ (N_B * 32 * 32 * 3)

// native clang vectors; f4u/f2u carry 4-byte alignment so the compiler may
// emit unaligned-global wide loads at 12B-multiple NHWC offsets.
typedef float v2f __attribute__((ext_vector_type(2)));
typedef float f4u __attribute__((ext_vector_type(4), aligned(4)));
typedef float f2u __attribute__((ext_vector_type(2), aligned(4)));

// ------------------------------------------------------------------
// Kernel 1: per-batch linear head -> affine matrix + level
// (numerics deliberately untouched: dot-order drives the absmax budget)
// ------------------------------------------------------------------
__global__ void params_kernel(const float* __restrict__ features,
                              const float* __restrict__ lin_w,
                              const float* __restrict__ lin_b,
                              float* __restrict__ out_matrix,
                              float* __restrict__ out_affine,
                              float* __restrict__ ws_params)
{
    const int n = blockIdx.x;
    const int t = threadIdx.x;
    const float* f = features + n * D_FEAT;
    float f0 = f[t];
    float f1 = f[t + 256];
    float a0 = f0 * lin_w[0 * D_FEAT + t] + f1 * lin_w[0 * D_FEAT + t + 256];
    float a1 = f0 * lin_w[1 * D_FEAT + t] + f1 * lin_w[1 * D_FEAT + t + 256];
    float a2 = f0 * lin_w[2 * D_FEAT + t] + f1 * lin_w[2 * D_FEAT + t + 256];
    float a3 = f0 * lin_w[3 * D_FEAT + t] + f1 * lin_w[3 * D_FEAT + t + 256];

    __shared__ float red[4][256];
    red[0][t] = a0; red[1][t] = a1; red[2][t] = a2; red[3][t] = a3;
    __syncthreads();
    for (int s = 128; s > 0; s >>= 1) {
        if (t < s) {
            red[0][t] += red[0][t + s];
            red[1][t] += red[1][t + s];
            red[2][t] += red[2][t + s];
            red[3][t] += red[3][t + s];
        }
        __syncthreads();
    }
    if (t == 0) {
        float p0 = red[0][0] + lin_b[0];
        float p1 = red[1][0] + lin_b[1];
        float p2 = red[2][0] + lin_b[2];
        float p3 = red[3][0] + lin_b[3];
        float rot   = tanhf(p0) * 3.14159265358979323846f;
        float scale = expf(p1);
        float c = cosf(rot), s = sinf(rot);
        float m00 = scale * c, m01 = -scale * s, m02 = p2;
        float m10 = scale * s, m11 =  scale * c, m12 = p3;
        out_matrix[n * 6 + 0] = m00;
        out_matrix[n * 6 + 1] = m01;
        out_matrix[n * 6 + 2] = m02;
        out_matrix[n * 6 + 3] = m10;
        out_matrix[n * 6 + 4] = m11;
        out_matrix[n * 6 + 5] = m12;
        out_affine[n * 4 + 0] = rot;
        out_affine[n * 4 + 1] = scale;
        out_affine[n * 4 + 2] = p2;
        out_affine[n * 4 + 3] = p3;
        // affine grid => Jacobian norm is exactly `scale` in both directions
        float lv = log2f(fmaxf(scale, 1.0f));
        lv = fminf(fmaxf(lv, 0.0f), 2.5f);
        ws_params[n * 8 + 0] = m00;
        ws_params[n * 8 + 1] = m01;
        ws_params[n * 8 + 2] = m02;
        ws_params[n * 8 + 3] = m10;
        ws_params[n * 8 + 4] = m11;
        ws_params[n * 8 + 5] = m12;
        ws_params[n * 8 + 6] = lv;
        ws_params[n * 8 + 7] = 0.0f;
    }
}

// ------------------------------------------------------------------
// Kernel 2a: level0 (NCHW img) -> level1 (NHWC pyr1).
// One thread = 4 consecutive output px x 3 channels: aligned float4
// A/B window + 2 edge scalars per row/channel (4 load-requests per
// output px), NHWC store is 48 contiguous bytes (3 aligned f4u).
// Gated per batch: lv>0 else plane never sampled.
// ------------------------------------------------------------------
__global__ void down1_kernel(const float* __restrict__ img,
                             float* __restrict__ pyr1,
                             const float* __restrict__ ws_params)
{
    const int n = blockIdx.y;
    if (ws_params[n * 8 + 6] <= 0.0f) return;
    const int idx = blockIdx.x * 256 + threadIdx.x;  // 0..4095
    const int t = idx & 31;          // quad (4 out px) in row
    const int i = idx >> 5;          // out row 0..127

    int r[4];
#pragma unroll
    for (int a = 0; a < 4; a++) {
        int q = 2 * i + a - 1;
        if (q < 0) q = -q;
        if (q >= 256) q = 510 - q;
        r[a] = q;
    }
    const int c8 = 8 * t;
    const int li = (t > 0)  ? c8 - 1 : 1;     // reflect -1 -> 1
    const int ri = (t < 31) ? c8 + 8 : 254;   // reflect 256 -> 254

    const float* s = img + (size_t)n * 3 * 65536;

    const float k0 = 0.125f, k1 = 0.375f;
    const float kr[4] = {0.125f, 0.375f, 0.375f, 0.125f};

    float acc[3][4] = {};
#pragma unroll
    for (int a = 0; a < 4; a++) {
        const float* rbase = s + (size_t)r[a] * 256;
        f4u A[3], B[3];
        float L[3], R[3];
#pragma unroll
        for (int c = 0; c < 3; c++) {
            const float* row = rbase + c * 65536;
            A[c] = *(const f4u*)(row + c8);
            B[c] = *(const f4u*)(row + c8 + 4);
            L[c] = row[li];
            R[c] = row[ri];
        }
#pragma unroll
        for (int c = 0; c < 3; c++) {
            float h0 = k0 * L[c]   + k1 * A[c].x + k1 * A[c].y + k0 * A[c].z;
            float h1 = k0 * A[c].y + k1 * A[c].z + k1 * A[c].w + k0 * B[c].x;
            float h2 = k0 * A[c].w + k1 * B[c].x + k1 * B[c].y + k0 * B[c].z;
            float h3 = k0 * B[c].y + k1 * B[c].z + k1 * B[c].w + k0 * R[c];
            acc[c][0] += kr[a] * h0;
            acc[c][1] += kr[a] * h1;
            acc[c][2] += kr[a] * h2;
            acc[c][3] += kr[a] * h3;
        }
    }
    // NHWC interleave: d[3q+c] = acc[c][q], 48B contiguous, 16B aligned
    float* d = pyr1 + (size_t)n * (128 * 128 * 3) + ((size_t)i * 128 + 4 * t) * 3;
    f4u s0 = {acc[0][0], acc[1][0], acc[2][0], acc[0][1]};
    f4u s1 = {acc[1][1], acc[2][1], acc[0][2], acc[1][2]};
    f4u s2 = {acc[2][2], acc[0][3], acc[1][3], acc[2][3]};
    *(f4u*)(d)     = s0;
    *(f4u*)(d + 4) = s1;
    *(f4u*)(d + 8) = s2;
}

// ------------------------------------------------------------------
// Kernel 2b: NHWC -> NHWC downsample (levels 2,3). One thread = one
// output pixel x 3 channels; per-tap f4 loads handle reflect uniformly.
// Gated to lv>1 (~6%) / lv>2 (~1%) of batches -> cost negligible.
// (f4 col reads may run 2 floats past the plane: lands in the next
// pyramid buffer, which directly follows in the workspace.)
// ------------------------------------------------------------------
template<int Hs, int Ws>
__global__ void downN_kernel(const float* __restrict__ src,
                             float* __restrict__ dst,
                             const float* __restrict__ ws_params,
                             float lvl_gate)
{
    const int n = blockIdx.y;
    if (ws_params[n * 8 + 6] <= lvl_gate) return;
    constexpr int Hd = Hs / 2, Wd = Ws / 2;
    const int p = blockIdx.x * 256 + threadIdx.x;
    const int i = p / Wd;
    const int j = p % Wd;

    int r[4], cc[4];
#pragma unroll
    for (int a = 0; a < 4; a++) {
        int q = 2 * i + a - 1;
        if (q < 0) q = -q;
        if (q >= Hs) q = 2 * Hs - 2 - q;
        r[a] = q;
        int u = 2 * j + a - 1;
        if (u < 0) u = -u;
        if (u >= Ws) u = 2 * Ws - 2 - u;
        cc[a] = u;
    }
    const float* s = src + (size_t)n * 3 * Hs * Ws;
    const int rs = 3 * Ws;

    f4u T[4][4];
#pragma unroll
    for (int a = 0; a < 4; a++)
#pragma unroll
        for (int b = 0; b < 4; b++)
            T[a][b] = *(const f4u*)(s + r[a] * rs + 3 * cc[b]);

    const float k0 = 0.125f, k1 = 0.375f;
    const float kr[4] = {0.125f, 0.375f, 0.375f, 0.125f};
    float o[3];
#pragma unroll
    for (int c = 0; c < 3; c++) {
        float acc = 0.0f;
#pragma unroll
        for (int a = 0; a < 4; a++) {
            float h = k0 * T[a][0][c] + k1 * T[a][1][c]
                    + k1 * T[a][2][c] + k0 * T[a][3][c];
            acc += kr[a] * h;
        }
        o[c] = acc;
    }
    float* d = dst + (size_t)n * 3 * Hd * Wd + (size_t)p * 3;
    d[0] = o[0]; d[1] = o[1]; d[2] = o[2];
}

// ------------------------------------------------------------------
// Kernel 3: affine grid + mipmap bilinear warp, 1 px/thread
// (round-1 version: best measured — 2 px/thread batching regressed;
// the limit is CU-level request throughput, not per-thread MLP).
// Level 0 gathers stay NCHW; pyramid levels gather NHWC (f4+f2 per row).
// ------------------------------------------------------------------
struct TapSetup {            // NCHW (level 0 only)
    const float* row0;
    const float* row1;
    float w00, w01, w10, w11;
    bool selHi0, selLo1;
    size_t planeStride;
};

__device__ __forceinline__ TapSetup make_taps(const float* __restrict__ base, int l,
                                              float X, float Y)
{
    const int Wl = W_IMG >> l;
    const int Hl = H_IMG >> l;
    float x = (X + 1.0f) * (0.5f * (float)Wl) - 0.5f;
    float y = (Y + 1.0f) * (0.5f * (float)Hl) - 0.5f;
    float x0f = floorf(x), y0f = floorf(y);
    float tx = x - x0f, ty = y - y0f;
    int x0 = (int)x0f, y0 = (int)y0f;
    int y0i = min(max(y0,     0), Hl - 1);
    int y1i = min(max(y0 + 1, 0), Hl - 1);
    int xp = min(max(x0, 0), Wl - 2);
    TapSetup ts;
    ts.row0 = base + (size_t)y0i * Wl + xp;
    ts.row1 = base + (size_t)y1i * Wl + xp;
    ts.selHi0 = (x0 >= Wl - 1);
    ts.selLo1 = (x0 < 0);
    ts.w00 = (1.0f - tx) * (1.0f - ty);
    ts.w01 = tx * (1.0f - ty);
    ts.w10 = (1.0f - tx) * ty;
    ts.w11 = tx * ty;
    ts.planeStride = (size_t)Hl * Wl;
    return ts;
}

__device__ __forceinline__ float tap_eval(const TapSetup& ts, float2 a, float2 b)
{
    float t00 = ts.selHi0 ? a.y : a.x;
    float t01 = ts.selLo1 ? a.x : a.y;
    float t10 = ts.selHi0 ? b.y : b.x;
    float t11 = ts.selLo1 ? b.x : b.y;
    return ts.w00 * t00 + ts.w01 * t01 + ts.w10 * t10 + ts.w11 * t11;
}

struct NTap {                // NHWC (levels 1..3)
    const float* r0;
    const float* r1;
    float w00, w01, w10, w11;
    bool hi, lo;
};

__device__ __forceinline__ NTap make_ntap(const float* __restrict__ base, int l,
                                          float X, float Y)
{
    const int Wl = W_IMG >> l;
    const int Hl = H_IMG >> l;
    float x = (X + 1.0f) * (0.5f * (float)Wl) - 0.5f;
    float y = (Y + 1.0f) * (0.5f * (float)Hl) - 0.5f;
    float x0f = floorf(x), y0f = floorf(y);
    float tx = x - x0f, ty = y - y0f;
    int x0 = (int)x0f, y0 = (int)y0f;
    int y0i = min(max(y0,     0), Hl - 1);
    int y1i = min(max(y0 + 1, 0), Hl - 1);
    int xp  = min(max(x0, 0), Wl - 2);
    const int rs = 3 * Wl;
    NTap t;
    t.r0 = base + (size_t)y0i * rs + 3 * xp;
    t.r1 = base + (size_t)y1i * rs + 3 * xp;
    t.hi = (x0 >= Wl - 1);
    t.lo = (x0 < 0);
    t.w00 = (1.0f - tx) * (1.0f - ty);
    t.w01 = tx * (1.0f - ty);
    t.w10 = (1.0f - tx) * ty;
    t.w11 = tx * ty;
    return t;
}

__device__ __forceinline__ void ntap_eval(const NTap& t, f4u a, f2u a2,
                                          f4u b, f2u b2, float* v)
{
    float e0[6] = {a.x, a.y, a.z, a.w, a2.x, a2.y};
    float e1[6] = {b.x, b.y, b.z, b.w, b2.x, b2.y};
#pragma unroll
    for (int c = 0; c < 3; c++) {
        float p00 = t.hi ? e0[c + 3] : e0[c];
        float p01 = t.lo ? e0[c]     : e0[c + 3];
        float p10 = t.hi ? e1[c + 3] : e1[c];
        float p11 = t.lo ? e1[c]     : e1[c + 3];
        v[c] = t.w00 * p00 + t.w01 * p01 + t.w10 * p10 + t.w11 * p11;
    }
}

__device__ __forceinline__ const float* npyr(int l, const float* p1,
                                             const float* p2, const float* p3,
                                             int n)
{
    if (l == 1) return p1 + (size_t)n * (128 * 128 * 3);
    if (l == 2) return p2 + (size_t)n * (64 * 64 * 3);
    return p3 + (size_t)n * (32 * 32 * 3);
}

__global__ __launch_bounds__(256, 4)
void warp_kernel(const float* __restrict__ img,
                 const float* __restrict__ pyr1,
                 const float* __restrict__ pyr2,
                 const float* __restrict__ pyr3,
                 const float* __restrict__ ws_params,
                 float* __restrict__ out,
                 float* __restrict__ gridOut)
{
    const int n = blockIdx.y;
    const int tile = blockIdx.x;
    const int tid = threadIdx.x;
    // block covers 32x8; each 64-lane wave covers a 16x4 sub-tile
    const int w0 = (tile & 7) << 5;
    const int h0 = (tile >> 3) << 3;
    const int w = w0 + (((tid >> 6) & 1) << 4) + (tid & 15);
    const int h = h0 + ((tid >> 7) << 2) + ((tid >> 4) & 3);

    const float* P = ws_params + n * 8;
    float m00 = P[0], m01 = P[1], m02 = P[2];
    float m10 = P[3], m11 = P[4], m12 = P[5];
    float lv  = P[6];

    float gx = ((float)w + 0.5f) * (2.0f / (float)W_IMG) - 1.0f;
    float gy = ((float)h + 0.5f) * (2.0f / (float)H_IMG) - 1.0f;
    float X = m00 * gx + m01 * gy + m02;
    float Y = m10 * gx + m11 * gy + m12;

    // grid output (N,H,W,2) — never re-read: one v2f nt-store (full lines)
    v2f gp = {X, Y};
    __builtin_nontemporal_store(gp, (v2f*)gridOut + ((size_t)(n * H_IMG + h) * W_IMG + w));

    int   l0   = (int)lv;          // lv in [0, 2.5]: trunc == floor
    float frac = lv - (float)l0;
    const bool hasL1 = (frac > 0.0f);   // batch-uniform
    const float wA = 1.0f - frac;

    size_t obase = ((size_t)n * C_CH * H_IMG + h) * W_IMG + w;

    if (l0 == 0) {
        const float* base0 = img + (size_t)n * 3 * 65536;
        TapSetup t0 = make_taps(base0, 0, X, Y);
        float2 A0[3], B0[3];
#pragma unroll
        for (int c = 0; c < 3; c++) {
            A0[c] = *(const float2*)(t0.row0 + c * t0.planeStride);
            B0[c] = *(const float2*)(t0.row1 + c * t0.planeStride);
        }
        if (hasL1) {
            NTap t1 = make_ntap(pyr1 + (size_t)n * (128 * 128 * 3), 1, X, Y);
            f4u a = *(const f4u*)t1.r0;  f2u a2 = *(const f2u*)(t1.r0 + 4);
            f4u b = *(const f4u*)t1.r1;  f2u b2 = *(const f2u*)(t1.r1 + 4);
            float v1[3];
            ntap_eval(t1, a, a2, b, b2, v1);
#pragma unroll
            for (int c = 0; c < 3; c++) {
                float v0 = tap_eval(t0, A0[c], B0[c]);
                __builtin_nontemporal_store(wA * v0 + frac * v1[c],
                                            out + obase + (size_t)c * 65536);
            }
        } else {
#pragma unroll
            for (int c = 0; c < 3; c++)
                __builtin_nontemporal_store(tap_eval(t0, A0[c], B0[c]),
                                            out + obase + (size_t)c * 65536);
        }
    } else {
        const float* base0 = npyr(l0, pyr1, pyr2, pyr3, n);
        NTap t0 = make_ntap(base0, l0, X, Y);
        f4u a = *(const f4u*)t0.r0;  f2u a2 = *(const f2u*)(t0.r0 + 4);
        f4u b = *(const f4u*)t0.r1;  f2u b2 = *(const f2u*)(t0.r1 + 4);
        if (hasL1) {
            const float* base1 = npyr(l0 + 1, pyr1, pyr2, pyr3, n);
            NTap t1 = make_ntap(base1, l0 + 1, X, Y);
            f4u c1 = *(const f4u*)t1.r0;  f2u c2 = *(const f2u*)(t1.r0 + 4);
            f4u d1 = *(const f4u*)t1.r1;  f2u d2 = *(const f2u*)(t1.r1 + 4);
            float v0[3], v1[3];
            ntap_eval(t0, a, a2, b, b2, v0);
            ntap_eval(t1, c1, c2, d1, d2, v1);
#pragma unroll
            for (int c = 0; c < 3; c++)
                __builtin_nontemporal_store(wA * v0[c] + frac * v1[c],
                                            out + obase + (size_t)c * 65536);
        } else {
            float v0[3];
            ntap_eval(t0, a, a2, b, b2, v0);
#pragma unroll
            for (int c = 0; c < 3; c++)
                __builtin_nontemporal_store(v0[c],
                                            out + obase + (size_t)c * 65536);
        }
    }
}

// ------------------------------------------------------------------
extern "C" void kernel_launch(void* const* d_in, const int* in_sizes, int n_in,
                              void* d_out, int out_size, void* d_ws, size_t ws_size,
                              hipStream_t stream)
{
    const float* img      = (const float*)d_in[0];
    const float* features = (const float*)d_in[1];
    const float* lin_w    = (const float*)d_in[2];
    const float* lin_b    = (const float*)d_in[3];

    float* out        = (float*)d_out;
    float* gridOut    = out + OUT_OFF_GRID;
    float* out_matrix = out + OUT_OFF_MATRIX;
    float* out_affine = out + OUT_OFF_AFFINE;

    float* ws        = (float*)d_ws;
    float* ws_params = ws;
    float* pyr1 = ws + 1024;            // NHWC 64x128x128x3
    float* pyr2 = pyr1 + PYR1_SZ;       // NHWC 64x64x64x3
    float* pyr3 = pyr2 + PYR2_SZ;       // NHWC 64x32x32x3

    params_kernel<<<N_B, 256, 0, stream>>>(features, lin_w, lin_b,
                                           out_matrix, out_affine, ws_params);

    // level L sampled only when lv > L-1  ->  gate = L-1
    down1_kernel<<<dim3(16, N_B), 256, 0, stream>>>(img, pyr1, ws_params);
    downN_kernel<128, 128><<<dim3(16, N_B), 256, 0, stream>>>(pyr1, pyr2, ws_params, 1.0f);
    downN_kernel<64, 64><<<dim3(4, N_B), 256, 0, stream>>>(pyr2, pyr3, ws_params, 2.0f);

    warp_kernel<<<dim3(H_IMG * W_IMG / 256, N_B), 256, 0, stream>>>(
        img, pyr1, pyr2, pyr3, ws_params, out, gridOut);
}

// Round 4
// 164.504 us; speedup vs baseline: 1.0555x; 1.0555x over previous
//
#include <hip/hip_runtime.h>
#include <math.h>

// Problem constants (N,C,H,W,D) = (64, 3, 256, 256, 512)
#define N_B 64
#define C_CH 3
#define H_IMG 256
#define W_IMG 256
#define D_FEAT 512

#define OUT_OFF_GRID   12582912
#define OUT_OFF_MATRIX 20971520
#define OUT_OFF_AFFINE 20971904

// pyramid (NHWC layout, c innermost) sizes in floats
#define PYR1_SZ (N_B * 128 * 128 * 3)
#define PYR2_SZ (N_B * 64 * 64 * 3)
#define PYR3_SZ (N_B * 32 * 32 * 3)

// native clang vectors; f4u/f2u carry 4-byte alignment so the compiler may
// emit unaligned-global wide loads at 12B-multiple NHWC offsets.
typedef float v2f __attribute__((ext_vector_type(2)));
typedef float v4f __attribute__((ext_vector_type(4)));
typedef float f4u __attribute__((ext_vector_type(4), aligned(4)));
typedef float f2u __attribute__((ext_vector_type(2), aligned(4)));

// ------------------------------------------------------------------
// Kernel 1: per-batch linear head -> affine matrix + level
// (numerics deliberately untouched: dot-order drives the absmax budget)
// ------------------------------------------------------------------
__global__ void params_kernel(const float* __restrict__ features,
                              const float* __restrict__ lin_w,
                              const float* __restrict__ lin_b,
                              float* __restrict__ out_matrix,
                              float* __restrict__ out_affine,
                              float* __restrict__ ws_params)
{
    const int n = blockIdx.x;
    const int t = threadIdx.x;
    const float* f = features + n * D_FEAT;
    float f0 = f[t];
    float f1 = f[t + 256];
    float a0 = f0 * lin_w[0 * D_FEAT + t] + f1 * lin_w[0 * D_FEAT + t + 256];
    float a1 = f0 * lin_w[1 * D_FEAT + t] + f1 * lin_w[1 * D_FEAT + t + 256];
    float a2 = f0 * lin_w[2 * D_FEAT + t] + f1 * lin_w[2 * D_FEAT + t + 256];
    float a3 = f0 * lin_w[3 * D_FEAT + t] + f1 * lin_w[3 * D_FEAT + t + 256];

    __shared__ float red[4][256];
    red[0][t] = a0; red[1][t] = a1; red[2][t] = a2; red[3][t] = a3;
    __syncthreads();
    for (int s = 128; s > 0; s >>= 1) {
        if (t < s) {
            red[0][t] += red[0][t + s];
            red[1][t] += red[1][t + s];
            red[2][t] += red[2][t + s];
            red[3][t] += red[3][t + s];
        }
        __syncthreads();
    }
    if (t == 0) {
        float p0 = red[0][0] + lin_b[0];
        float p1 = red[1][0] + lin_b[1];
        float p2 = red[2][0] + lin_b[2];
        float p3 = red[3][0] + lin_b[3];
        float rot   = tanhf(p0) * 3.14159265358979323846f;
        float scale = expf(p1);
        float c = cosf(rot), s = sinf(rot);
        float m00 = scale * c, m01 = -scale * s, m02 = p2;
        float m10 = scale * s, m11 =  scale * c, m12 = p3;
        out_matrix[n * 6 + 0] = m00;
        out_matrix[n * 6 + 1] = m01;
        out_matrix[n * 6 + 2] = m02;
        out_matrix[n * 6 + 3] = m10;
        out_matrix[n * 6 + 4] = m11;
        out_matrix[n * 6 + 5] = m12;
        out_affine[n * 4 + 0] = rot;
        out_affine[n * 4 + 1] = scale;
        out_affine[n * 4 + 2] = p2;
        out_affine[n * 4 + 3] = p3;
        // affine grid => Jacobian norm is exactly `scale` in both directions
        float lv = log2f(fmaxf(scale, 1.0f));
        lv = fminf(fmaxf(lv, 0.0f), 2.5f);
        ws_params[n * 8 + 0] = m00;
        ws_params[n * 8 + 1] = m01;
        ws_params[n * 8 + 2] = m02;
        ws_params[n * 8 + 3] = m10;
        ws_params[n * 8 + 4] = m11;
        ws_params[n * 8 + 5] = m12;
        ws_params[n * 8 + 6] = lv;
        ws_params[n * 8 + 7] = 0.0f;
    }
}

// ------------------------------------------------------------------
// Kernel 2a: level0 (NCHW img) -> level1 (NHWC pyr1).  Round-1 form:
// 1 px x 3ch per thread (max waves for latency hiding), clamped f4u
// window per tap row (no scalar edge loads). Gated per batch: lv>0.
// ------------------------------------------------------------------
__global__ void down1_kernel(const float* __restrict__ img,
                             float* __restrict__ pyr1,
                             const float* __restrict__ ws_params)
{
    const int n = blockIdx.y;
    if (ws_params[n * 8 + 6] <= 0.0f) return;
    const int p = blockIdx.x * 256 + threadIdx.x;   // 0..16383
    const int i = p >> 7;        // out row 0..127
    const int j = p & 127;       // out col 0..127

    int r[4];
#pragma unroll
    for (int a = 0; a < 4; a++) {
        int q = 2 * i + a - 1;
        if (q < 0) q = -q;
        if (q >= 256) q = 510 - q;
        r[a] = q;
    }
    // horizontal taps are cols 2j-1..2j+2; a clamped float4 window always
    // contains every reflected tap: j==0 -> {1,0,1,2}, j==127 -> {1,2,3,2}
    const int  cb  = min(max(2 * j - 1, 0), 252);
    const bool jlo = (j == 0);
    const bool jhi = (j == 127);
    const bool je  = jlo || jhi;

    const float* s = img + (size_t)n * 3 * 65536;

    f4u T[3][4];
#pragma unroll
    for (int c = 0; c < 3; c++)
#pragma unroll
        for (int a = 0; a < 4; a++)
            T[c][a] = *(const f4u*)(s + c * 65536 + r[a] * 256 + cb);

    const float k0 = 0.125f, k1 = 0.375f;
    const float kr[4] = {0.125f, 0.375f, 0.375f, 0.125f};
    float o[3];
#pragma unroll
    for (int c = 0; c < 3; c++) {
        float acc = 0.0f;
#pragma unroll
        for (int a = 0; a < 4; a++) {
            f4u A = T[c][a];
            float t0 = je  ? A.y : A.x;
            float t1 = jlo ? A.x : (jhi ? A.z : A.y);
            float t2 = jlo ? A.y : (jhi ? A.w : A.z);
            float t3 = je  ? A.z : A.w;
            float h = k0 * t0 + k1 * t1 + k1 * t2 + k0 * t3;
            acc += kr[a] * h;
        }
        o[c] = acc;
    }
    float* d = pyr1 + (size_t)n * (128 * 128 * 3) + (size_t)p * 3;
    d[0] = o[0]; d[1] = o[1]; d[2] = o[2];
}

// ------------------------------------------------------------------
// Kernel 2b: NHWC -> NHWC downsample (levels 2,3). One thread = one
// output pixel x 3 channels; per-tap f4 loads handle reflect uniformly.
// Gated to lv>1 (~6%) / lv>2 (~1%) of batches -> cost negligible.
// (f4 col reads may run 2 floats past the plane: lands in the next
// pyramid buffer, which directly follows in the workspace.)
// ------------------------------------------------------------------
template<int Hs, int Ws>
__global__ void downN_kernel(const float* __restrict__ src,
                             float* __restrict__ dst,
                             const float* __restrict__ ws_params,
                             float lvl_gate)
{
    const int n = blockIdx.y;
    if (ws_params[n * 8 + 6] <= lvl_gate) return;
    constexpr int Hd = Hs / 2, Wd = Ws / 2;
    const int p = blockIdx.x * 256 + threadIdx.x;
    const int i = p / Wd;
    const int j = p % Wd;

    int r[4], cc[4];
#pragma unroll
    for (int a = 0; a < 4; a++) {
        int q = 2 * i + a - 1;
        if (q < 0) q = -q;
        if (q >= Hs) q = 2 * Hs - 2 - q;
        r[a] = q;
        int u = 2 * j + a - 1;
        if (u < 0) u = -u;
        if (u >= Ws) u = 2 * Ws - 2 - u;
        cc[a] = u;
    }
    const float* s = src + (size_t)n * 3 * Hs * Ws;
    const int rs = 3 * Ws;

    f4u T[4][4];
#pragma unroll
    for (int a = 0; a < 4; a++)
#pragma unroll
        for (int b = 0; b < 4; b++)
            T[a][b] = *(const f4u*)(s + r[a] * rs + 3 * cc[b]);

    const float k0 = 0.125f, k1 = 0.375f;
    const float kr[4] = {0.125f, 0.375f, 0.375f, 0.125f};
    float o[3];
#pragma unroll
    for (int c = 0; c < 3; c++) {
        float acc = 0.0f;
#pragma unroll
        for (int a = 0; a < 4; a++) {
            float h = k0 * T[a][0][c] + k1 * T[a][1][c]
                    + k1 * T[a][2][c] + k0 * T[a][3][c];
            acc += kr[a] * h;
        }
        o[c] = acc;
    }
    float* d = dst + (size_t)n * 3 * Hd * Wd + (size_t)p * 3;
    d[0] = o[0]; d[1] = o[1]; d[2] = o[2];
}

// ------------------------------------------------------------------
// Kernel 3: affine grid + mipmap bilinear warp, 2 px/thread ALONG W
// (w even). Loads can't be shared (rotation), but stores vectorize:
// 3x v2f (out) + 1x f4 (grid) = 2 store requests/px instead of 4.
// Per-px arithmetic identical to the 1px version.
// ------------------------------------------------------------------
struct TapSetup {            // NCHW (level 0 only)
    const float* row0;
    const float* row1;
    float w00, w01, w10, w11;
    bool selHi0, selLo1;
    size_t planeStride;
};

__device__ __forceinline__ TapSetup make_taps(const float* __restrict__ base, int l,
                                              float X, float Y)
{
    const int Wl = W_IMG >> l;
    const int Hl = H_IMG >> l;
    float x = (X + 1.0f) * (0.5f * (float)Wl) - 0.5f;
    float y = (Y + 1.0f) * (0.5f * (float)Hl) - 0.5f;
    float x0f = floorf(x), y0f = floorf(y);
    float tx = x - x0f, ty = y - y0f;
    int x0 = (int)x0f, y0 = (int)y0f;
    int y0i = min(max(y0,     0), Hl - 1);
    int y1i = min(max(y0 + 1, 0), Hl - 1);
    int xp = min(max(x0, 0), Wl - 2);
    TapSetup ts;
    ts.row0 = base + (size_t)y0i * Wl + xp;
    ts.row1 = base + (size_t)y1i * Wl + xp;
    ts.selHi0 = (x0 >= Wl - 1);
    ts.selLo1 = (x0 < 0);
    ts.w00 = (1.0f - tx) * (1.0f - ty);
    ts.w01 = tx * (1.0f - ty);
    ts.w10 = (1.0f - tx) * ty;
    ts.w11 = tx * ty;
    ts.planeStride = (size_t)Hl * Wl;
    return ts;
}

__device__ __forceinline__ float tap_eval(const TapSetup& ts, float2 a, float2 b)
{
    float t00 = ts.selHi0 ? a.y : a.x;
    float t01 = ts.selLo1 ? a.x : a.y;
    float t10 = ts.selHi0 ? b.y : b.x;
    float t11 = ts.selLo1 ? b.x : b.y;
    return ts.w00 * t00 + ts.w01 * t01 + ts.w10 * t10 + ts.w11 * t11;
}

struct NTap {                // NHWC (levels 1..3)
    const float* r0;
    const float* r1;
    float w00, w01, w10, w11;
    bool hi, lo;
};

__device__ __forceinline__ NTap make_ntap(const float* __restrict__ base, int l,
                                          float X, float Y)
{
    const int Wl = W_IMG >> l;
    const int Hl = H_IMG >> l;
    float x = (X + 1.0f) * (0.5f * (float)Wl) - 0.5f;
    float y = (Y + 1.0f) * (0.5f * (float)Hl) - 0.5f;
    float x0f = floorf(x), y0f = floorf(y);
    float tx = x - x0f, ty = y - y0f;
    int x0 = (int)x0f, y0 = (int)y0f;
    int y0i = min(max(y0,     0), Hl - 1);
    int y1i = min(max(y0 + 1, 0), Hl - 1);
    int xp  = min(max(x0, 0), Wl - 2);
    const int rs = 3 * Wl;
    NTap t;
    t.r0 = base + (size_t)y0i * rs + 3 * xp;
    t.r1 = base + (size_t)y1i * rs + 3 * xp;
    t.hi = (x0 >= Wl - 1);
    t.lo = (x0 < 0);
    t.w00 = (1.0f - tx) * (1.0f - ty);
    t.w01 = tx * (1.0f - ty);
    t.w10 = (1.0f - tx) * ty;
    t.w11 = tx * ty;
    return t;
}

struct NPay { f4u a; f2u a2; f4u b; f2u b2; };

__device__ __forceinline__ NPay ntap_load(const NTap& t)
{
    NPay p;
    p.a  = *(const f4u*)t.r0;  p.a2 = *(const f2u*)(t.r0 + 4);
    p.b  = *(const f4u*)t.r1;  p.b2 = *(const f2u*)(t.r1 + 4);
    return p;
}

__device__ __forceinline__ void ntap_eval(const NTap& t, const NPay& p, float* v)
{
    float e0[6] = {p.a.x, p.a.y, p.a.z, p.a.w, p.a2.x, p.a2.y};
    float e1[6] = {p.b.x, p.b.y, p.b.z, p.b.w, p.b2.x, p.b2.y};
#pragma unroll
    for (int c = 0; c < 3; c++) {
        float p00 = t.hi ? e0[c + 3] : e0[c];
        float p01 = t.lo ? e0[c]     : e0[c + 3];
        float p10 = t.hi ? e1[c + 3] : e1[c];
        float p11 = t.lo ? e1[c]     : e1[c + 3];
        v[c] = t.w00 * p00 + t.w01 * p01 + t.w10 * p10 + t.w11 * p11;
    }
}

__device__ __forceinline__ const float* npyr(int l, const float* p1,
                                             const float* p2, const float* p3,
                                             int n)
{
    if (l == 1) return p1 + (size_t)n * (128 * 128 * 3);
    if (l == 2) return p2 + (size_t)n * (64 * 64 * 3);
    return p3 + (size_t)n * (32 * 32 * 3);
}

__global__ __launch_bounds__(256, 4)
void warp_kernel(const float* __restrict__ img,
                 const float* __restrict__ pyr1,
                 const float* __restrict__ pyr2,
                 const float* __restrict__ pyr3,
                 const float* __restrict__ ws_params,
                 float* __restrict__ out,
                 float* __restrict__ gridOut)
{
    const int n = blockIdx.y;
    const int tile = blockIdx.x;          // 128 tiles of 32x16
    const int tid = threadIdx.x;
    // thread owns px (w,h) and (w+1,h), w even; a wave covers 32x4
    const int w0 = (tile & 7) << 5;
    const int h0 = (tile >> 3) << 4;
    const int w  = w0 + ((tid & 15) << 1);
    const int h  = h0 + (tid >> 4);

    const float* P = ws_params + n * 8;
    float m00 = P[0], m01 = P[1], m02 = P[2];
    float m10 = P[3], m11 = P[4], m12 = P[5];
    float lv  = P[6];

    float gxa = ((float)w + 0.5f) * (2.0f / (float)W_IMG) - 1.0f;
    float gxb = ((float)(w + 1) + 0.5f) * (2.0f / (float)W_IMG) - 1.0f;
    float gy  = ((float)h + 0.5f) * (2.0f / (float)H_IMG) - 1.0f;
    float Xa = m00 * gxa + m01 * gy + m02;
    float Ya = m10 * gxa + m11 * gy + m12;
    float Xb = m00 * gxb + m01 * gy + m02;
    float Yb = m10 * gxb + m11 * gy + m12;

    // grid output (N,H,W,2): 2 px = 4 consecutive floats, 16B aligned
    v4f gp = {Xa, Ya, Xb, Yb};
    __builtin_nontemporal_store(gp,
        (v4f*)(gridOut + ((size_t)(n * H_IMG + h) * W_IMG + w) * 2));

    int   l0   = (int)lv;          // lv in [0, 2.5]: trunc == floor
    float frac = lv - (float)l0;
    const bool hasL1 = (frac > 0.0f);   // batch-uniform
    const float wA = 1.0f - frac;

    size_t obase = ((size_t)n * C_CH * H_IMG + h) * W_IMG + w;

    if (l0 == 0) {
        const float* base0 = img + (size_t)n * 3 * 65536;
        TapSetup ta = make_taps(base0, 0, Xa, Ya);
        TapSetup tb = make_taps(base0, 0, Xb, Yb);
        float2 Aa[3], Ba[3], Ab[3], Bb[3];
#pragma unroll
        for (int c = 0; c < 3; c++) {
            Aa[c] = *(const float2*)(ta.row0 + c * 65536);
            Ba[c] = *(const float2*)(ta.row1 + c * 65536);
            Ab[c] = *(const float2*)(tb.row0 + c * 65536);
            Bb[c] = *(const float2*)(tb.row1 + c * 65536);
        }
        if (hasL1) {
            const float* b1 = pyr1 + (size_t)n * (128 * 128 * 3);
            NTap ua = make_ntap(b1, 1, Xa, Ya);
            NTap ub = make_ntap(b1, 1, Xb, Yb);
            NPay pa = ntap_load(ua);
            NPay pb = ntap_load(ub);
            float v1a[3], v1b[3];
            ntap_eval(ua, pa, v1a);
            ntap_eval(ub, pb, v1b);
#pragma unroll
            for (int c = 0; c < 3; c++) {
                float v0a = tap_eval(ta, Aa[c], Ba[c]);
                float v0b = tap_eval(tb, Ab[c], Bb[c]);
                v2f o2 = {wA * v0a + frac * v1a[c], wA * v0b + frac * v1b[c]};
                __builtin_nontemporal_store(o2,
                    (v2f*)(out + obase + (size_t)c * 65536));
            }
        } else {
#pragma unroll
            for (int c = 0; c < 3; c++) {
                v2f o2 = {tap_eval(ta, Aa[c], Ba[c]), tap_eval(tb, Ab[c], Bb[c])};
                __builtin_nontemporal_store(o2,
                    (v2f*)(out + obase + (size_t)c * 65536));
            }
        }
    } else {
        const float* base0 = npyr(l0, pyr1, pyr2, pyr3, n);
        NTap ta = make_ntap(base0, l0, Xa, Ya);
        NTap tb = make_ntap(base0, l0, Xb, Yb);
        NPay pa = ntap_load(ta);
        NPay pb = ntap_load(tb);
        if (hasL1) {
            const float* base1 = npyr(l0 + 1, pyr1, pyr2, pyr3, n);
            NTap ua = make_ntap(base1, l0 + 1, Xa, Ya);
            NTap ub = make_ntap(base1, l0 + 1, Xb, Yb);
            NPay qa = ntap_load(ua);
            NPay qb = ntap_load(ub);
            float v0a[3], v0b[3], v1a[3], v1b[3];
            ntap_eval(ta, pa, v0a);
            ntap_eval(tb, pb, v0b);
            ntap_eval(ua, qa, v1a);
            ntap_eval(ub, qb, v1b);
#pragma unroll
            for (int c = 0; c < 3; c++) {
                v2f o2 = {wA * v0a[c] + frac * v1a[c], wA * v0b[c] + frac * v1b[c]};
                __builtin_nontemporal_store(o2,
                    (v2f*)(out + obase + (size_t)c * 65536));
            }
        } else {
            float v0a[3], v0b[3];
            ntap_eval(ta, pa, v0a);
            ntap_eval(tb, pb, v0b);
#pragma unroll
            for (int c = 0; c < 3; c++) {
                v2f o2 = {v0a[c], v0b[c]};
                __builtin_nontemporal_store(o2,
                    (v2f*)(out + obase + (size_t)c * 65536));
            }
        }
    }
}

// ------------------------------------------------------------------
extern "C" void kernel_launch(void* const* d_in, const int* in_sizes, int n_in,
                              void* d_out, int out_size, void* d_ws, size_t ws_size,
                              hipStream_t stream)
{
    const float* img      = (const float*)d_in[0];
    const float* features = (const float*)d_in[1];
    const float* lin_w    = (const float*)d_in[2];
    const float* lin_b    = (const float*)d_in[3];

    float* out        = (float*)d_out;
    float* gridOut    = out + OUT_OFF_GRID;
    float* out_matrix = out + OUT_OFF_MATRIX;
    float* out_affine = out + OUT_OFF_AFFINE;

    float* ws        = (float*)d_ws;
    float* ws_params = ws;
    float* pyr1 = ws + 1024;            // NHWC 64x128x128x3
    float* pyr2 = pyr1 + PYR1_SZ;       // NHWC 64x64x64x3
    float* pyr3 = pyr2 + PYR2_SZ;       // NHWC 64x32x32x3

    params_kernel<<<N_B, 256, 0, stream>>>(features, lin_w, lin_b,
                                           out_matrix, out_affine, ws_params);

    // level L sampled only when lv > L-1  ->  gate = L-1
    down1_kernel<<<dim3(64, N_B), 256, 0, stream>>>(img, pyr1, ws_params);
    downN_kernel<128, 128><<<dim3(16, N_B), 256, 0, stream>>>(pyr1, pyr2, ws_params, 1.0f);
    downN_kernel<64, 64><<<dim3(4, N_B), 256, 0, stream>>>(pyr2, pyr3, ws_params, 2.0f);

    warp_kernel<<<dim3(H_IMG * W_IMG / 512, N_B), 256, 0, stream>>>(
        img, pyr1, pyr2, pyr3, ws_params, out, gridOut);
}